// Round 6
// baseline (94.820 us; speedup 1.0000x reference)
//
#include <hip/hip_runtime.h>

// Per-element MLP 1->32->(32x32)x9->1, leaky relu, v_mfma_f32_32x32x16_f16.
// R11: R10 (16x16 shape + rotation + fdot2, all at once) was ~= R9 within
// harness noise -- confounded probe. R11 isolates the mechanism-backed
// levers on the R9 base (best measured, ~36us est):
//  1) weight/bias ROTATION: R9 waits ~120cyc lgkm at the top of every layer
//     (ds_read -> first MFMA). Prefetching layer l+1's wlo/whi/bc before
//     layer l's MFMAs takes that wait off the serial path (~300->~180
//     cyc/layer).
//  2) s_setprio(1) around the MFMA cluster: waves here are independent
//     (no barriers in main loop) = the attn-like regime where setprio
//     measured +4-7% (T5), not the GEMM-lockstep null regime.
//  3) fdot2 output layer (validated in R10, same absmax): -48 VALU/iter.
// Everything else is R9 verbatim: LDS pre-permuted weights, rolled layer
// loop (the R6/R7 spill fix), bias in lo-MFMA C operand, NCHAIN=4 in groups
// of 2, (256,3), grid 768.
#define NLAYERS 9
#define HID 32
#define SLOPE 0.01f

typedef _Float16 v2h __attribute__((ext_vector_type(2)));
typedef _Float16 v8h __attribute__((ext_vector_type(8)));
typedef float v16f __attribute__((ext_vector_type(16)));

#define NCHAIN 4

union U8 { v8h v; v2h p[4]; };          // B-operand half (16 f16 = 4 VGPRs)

__device__ __forceinline__ v2h pk_cvt(float a, float b) {
    return __builtin_bit_cast(v2h, __builtin_amdgcn_cvt_pkrtz(a, b));
}
__device__ __forceinline__ v2h leaky2(v2h t, v2h s) {
    return __builtin_elementwise_max(t, t * s);
}
// B-operand physical slot k -> logical hidden unit (weight-side permutation)
__device__ __forceinline__ int qmap(int k) {
    int c = k >> 4, h = (k >> 3) & 1, t = k & 7;
    return 16 * c + 4 * h + (t & 3) + 8 * (t >> 2);
}
// C/D reg -> physical row
__device__ __forceinline__ int rmap(int reg, int h) {
    return (reg & 3) + 8 * (reg >> 2) + 4 * h;
}

__global__ __launch_bounds__(256, 3) void mlp_mfma_kernel(
    const float* __restrict__ x,
    const float* __restrict__ W_in,   // [1,32]
    const float* __restrict__ b_in,   // [32]
    const float* __restrict__ W_hid,  // [9,32,32]  W[l][k_in][n_out]
    const float* __restrict__ b_hid,  // [9,32]
    const float* __restrict__ W_out,  // [32,1]
    const float* __restrict__ b_out,  // [1]
    float* __restrict__ out, int N)
{
    // Pre-permuted per-lane weight fragments: lane reads 16B contiguous
    // (64 lanes x 16B = 1024B -> conflict-free, verified 0 conflicts in R7).
    __shared__ __align__(16) _Float16 wlo_sh[NLAYERS][64][8];  // 9 KiB
    __shared__ __align__(16) _Float16 whi_sh[NLAYERS][64][8];  // 9 KiB
    // f32 bias in MFMA C layout: reg r of half hf <- b_hid[rmap(r,hf)]
    __shared__ __align__(64) float bc_sh[NLAYERS][2][16];      // 1.1 KiB

    const int tid = threadIdx.x;
    for (int t = tid; t < NLAYERS * 64; t += blockDim.x) {
        int l = t >> 6, ln = t & 63, hf = (ln >> 5) & 1, mm = ln & 31;
        const float* Wl = W_hid + l * HID * HID;
        v8h lo, hi;
#pragma unroll
        for (int j = 0; j < 8; ++j) {
            lo[j] = (_Float16)Wl[qmap(8 * hf + j) * HID + mm];
            hi[j] = (_Float16)Wl[qmap(16 + 8 * hf + j) * HID + mm];
        }
        *(v8h*)&wlo_sh[l][ln][0] = lo;
        *(v8h*)&whi_sh[l][ln][0] = hi;
    }
    for (int t = tid; t < NLAYERS * 32; t += blockDim.x) {
        int l = t >> 5, r = t & 31, hf = r >> 4, reg = r & 15;
        bc_sh[l][hf][reg] = b_hid[l * HID + rmap(reg, hf)];
    }
    __syncthreads();

    const int lane = tid & 63;
    const int half = lane >> 5;
    const int m    = lane & 31;   // batch col within tile

    // ---- register-resident io-layer fragments (24 VGPRs) ----
    v2h win2[8], bin2[8], wout2[8];
#pragma unroll
    for (int u = 0; u < 8; ++u) {
        int i0 = 2 * u, i1 = 2 * u + 1;
        int d0 = qmap(((i0 >> 3) << 4) + 8 * half + (i0 & 7));
        int d1 = qmap(((i1 >> 3) << 4) + 8 * half + (i1 & 7));
        win2[u]  = v2h{(_Float16)W_in[d0],  (_Float16)W_in[d1]};
        bin2[u]  = v2h{(_Float16)b_in[d0],  (_Float16)b_in[d1]};
        wout2[u] = v2h{(_Float16)W_out[d0], (_Float16)W_out[d1]};
    }
    const float bo = b_out[0];
    const v2h slope2 = v2h{(_Float16)SLOPE, (_Float16)SLOPE};

    const int nwaves = (gridDim.x * blockDim.x) >> 6;
    const int wid    = (blockIdx.x * blockDim.x + tid) >> 6;
    const int niter  = (N + NCHAIN * 32 - 1) / (NCHAIN * 32);

    // ---- x prefetch for first iteration ----
    float xc[NCHAIN] = {0.0f, 0.0f, 0.0f, 0.0f};
    if (wid < niter) {
#pragma unroll
        for (int c = 0; c < NCHAIN; ++c) {
            int idx = wid * (NCHAIN * 32) + c * 32 + m;
            xc[c] = (idx < N) ? x[idx] : 0.0f;
        }
    }

    for (int it = wid; it < niter; it += nwaves) {
        // prefetch next iteration's x (hides HBM latency under compute)
        float xn[NCHAIN] = {0.0f, 0.0f, 0.0f, 0.0f};
        {
            int nit = it + nwaves;
            if (nit < niter) {
#pragma unroll
                for (int c = 0; c < NCHAIN; ++c) {
                    int idx = nit * (NCHAIN * 32) + c * 32 + m;
                    xn[c] = (idx < N) ? x[idx] : 0.0f;
                }
            }
        }

        // ---- input layer, all chains ----
        U8 clo[NCHAIN], chi[NCHAIN];
#pragma unroll
        for (int c = 0; c < NCHAIN; ++c) {
            _Float16 xh = (_Float16)xc[c];
            v2h x2 = v2h{xh, xh};
#pragma unroll
            for (int u = 0; u < 4; ++u) {
                clo[c].p[u] = leaky2(x2 * win2[u] + bin2[u], slope2);
                chi[c].p[u] = leaky2(x2 * win2[4 + u] + bin2[4 + u], slope2);
            }
        }

        // ---- 9 hidden layers: REAL loop (no unroll; R6/R7 spill lesson),
        // next-layer weight/bias fragments rotated in ahead of use so the
        // ds_read lgkm wait overlaps layer l's MFMAs+epilogue ----
        v8h wlo = *(const v8h*)&wlo_sh[0][lane][0];
        v8h whi = *(const v8h*)&whi_sh[0][lane][0];
        v16f bc = *(const v16f*)&bc_sh[0][half][0];
#pragma unroll 1
        for (int l = 0; l < NLAYERS; ++l) {
            const int lnx = (l + 1 < NLAYERS) ? l + 1 : l;
            v8h wlo_n = *(const v8h*)&wlo_sh[lnx][lane][0];
            v8h whi_n = *(const v8h*)&whi_sh[lnx][lane][0];
            v16f bc_n = *(const v16f*)&bc_sh[lnx][half][0];
            // chains in groups of 2: 32 acc regs live; 2 independent groups
            // -> epilogue(g) overlaps MFMAs(g+1); bias rides in lo-MFMA C.
#pragma unroll
            for (int g = 0; g < NCHAIN / 2; ++g) {
                const int c0 = 2 * g, c1 = 2 * g + 1;
                __builtin_amdgcn_s_setprio(1);   // favor MFMA-issuing wave
                v16f a0 = __builtin_amdgcn_mfma_f32_32x32x16_f16(wlo, clo[c0].v, bc, 0, 0, 0);
                v16f a1 = __builtin_amdgcn_mfma_f32_32x32x16_f16(wlo, clo[c1].v, bc, 0, 0, 0);
                a0 = __builtin_amdgcn_mfma_f32_32x32x16_f16(whi, chi[c0].v, a0, 0, 0, 0);
                a1 = __builtin_amdgcn_mfma_f32_32x32x16_f16(whi, chi[c1].v, a1, 0, 0, 0);
                __builtin_amdgcn_s_setprio(0);
#pragma unroll
                for (int u = 0; u < 4; ++u) {
                    clo[c0].p[u] = leaky2(pk_cvt(a0[2 * u], a0[2 * u + 1]), slope2);
                    chi[c0].p[u] = leaky2(pk_cvt(a0[8 + 2 * u], a0[8 + 2 * u + 1]), slope2);
                    clo[c1].p[u] = leaky2(pk_cvt(a1[2 * u], a1[2 * u + 1]), slope2);
                    chi[c1].p[u] = leaky2(pk_cvt(a1[8 + 2 * u], a1[8 + 2 * u + 1]), slope2);
                }
            }
            wlo = wlo_n; whi = whi_n; bc = bc_n;
        }

        // ---- output layer: fdot2 (1 instr per v2h pair vs 4 cvt+fma) ----
#pragma unroll
        for (int c = 0; c < NCHAIN; ++c) {
            float p = 0.0f;
#pragma unroll
            for (int u = 0; u < 4; ++u) {
                p = __builtin_amdgcn_fdot2(clo[c].p[u], wout2[u], p, false);
                p = __builtin_amdgcn_fdot2(chi[c].p[u], wout2[4 + u], p, false);
            }
            float o = p + __shfl_xor(p, 32, 64) + bo;   // full sum in all lanes
            int idx = it * (NCHAIN * 32) + c * 32 + m;
            // split the 4 stores across the two halves (2 per lane)
            if (half == (c >> 1) && idx < N) out[idx] = o;
        }

#pragma unroll
        for (int c = 0; c < NCHAIN; ++c) xc[c] = xn[c];
    }
}

extern "C" void kernel_launch(void* const* d_in, const int* in_sizes, int n_in,
                              void* d_out, int out_size, void* d_ws, size_t ws_size,
                              hipStream_t stream) {
    const float* x     = (const float*)d_in[0];
    const float* W_in  = (const float*)d_in[1];
    const float* b_in  = (const float*)d_in[2];
    const float* W_hid = (const float*)d_in[3];
    const float* b_hid = (const float*)d_in[4];
    const float* W_out = (const float*)d_in[5];
    const float* b_out = (const float*)d_in[6];
    float* out = (float*)d_out;

    int N = in_sizes[0];
    // 768 blocks x 4 waves = 3072 waves = 3 waves/SIMD (168-reg budget,
    // rolled layer loop keeps liveness ~150 with rotation; 19.6 KiB LDS x 3
    // = 58.8 KiB/CU). niter = 8192 -> 2-3 iterations/wave.
    dim3 block(256);
    dim3 grid(768);
    mlp_mfma_kernel<<<grid, block, 0, stream>>>(x, W_in, b_in, W_hid, b_hid,
                                                W_out, b_out, out, N);
}